// Round 4
// baseline (624.386 us; speedup 1.0000x reference)
//
#include <hip/hip_runtime.h>

typedef _Float16 f16;
typedef _Float16 f16x8 __attribute__((ext_vector_type(8)));
typedef float    f32x4 __attribute__((ext_vector_type(4)));

#define BSZ 4
#define SL  2048
#define NK  24
#define DD  512
#define NPP 134   // p' = 2n+m+6 in [0,133]

typedef const void GV __attribute__((address_space(1)));
typedef void       LV __attribute__((address_space(3)));

__device__ __forceinline__ void gload_lds16(const void* gp, void* lp) {
  // dest = lp (wave-uniform) + lane*16
  __builtin_amdgcn_global_load_lds((GV*)gp, (LV*)lp, 16, 0, 0);
}

// ---------------- prep: A-fragment table
// afrag[i][p'][lane][j] = val(2047 - 16*(p'-6) - (lane&15) + 8*(lane>>4) + j)
// val(x) = (0<=x<2048) ? v[2047-x, i] * lam_i^0.25 : 0
__global__ void k_afrag(const float* __restrict__ eig_vals,
                        const float* __restrict__ eig_vecs,
                        f16* __restrict__ afrag) {
  int i = blockIdx.x, pp = blockIdx.y;
  int l = threadIdx.x;  // 64
  float sc = sqrtf(sqrtf(eig_vals[i]));
  int base = 2047 - 16 * (pp - 6) - (l & 15) + 8 * (l >> 4);
  f16 tmp[8];
#pragma unroll
  for (int j = 0; j < 8; ++j) {
    int x = base + j;
    float v = (x >= 0 && x < SL) ? eig_vecs[(size_t)(SL - 1 - x) * NK + i] * sc : 0.f;
    tmp[j] = (f16)v;
  }
  *(f16x8*)(afrag + (((size_t)i * NPP + pp) * 64 + l) * 8) = *(const f16x8*)tmp;
}

// ---------------- prep: ut[b][d][s] = (f16) u[b][s][d]
__global__ void k_tu(const float* __restrict__ u, f16* __restrict__ ut) {
  __shared__ float tile[32][33];
  int b = blockIdx.z;
  int s0 = blockIdx.x * 32, d0 = blockIdx.y * 32;
  int tx = threadIdx.x, ty = threadIdx.y;
#pragma unroll
  for (int r = 0; r < 4; ++r) {
    int s = s0 + ty * 4 + r;
    tile[ty * 4 + r][tx] = u[((size_t)b * SL + s) * DD + d0 + tx];
  }
  __syncthreads();
#pragma unroll
  for (int r = 0; r < 4; ++r) {
    int d = d0 + ty * 4 + r;
    ut[((size_t)b * DD + d) * SL + s0 + tx] = (f16)tile[tx][ty * 4 + r];
  }
}

// ---------------- prep: mht[e][k] = (f16) m_phi[k][e]   (B^T layout)
__global__ void k_tm(const float* __restrict__ mp, f16* __restrict__ mht) {
  __shared__ float tile[32][33];
  int k0 = blockIdx.x * 32, e0 = blockIdx.y * 32;
  int tx = threadIdx.x, ty = threadIdx.y;
#pragma unroll
  for (int r = 0; r < 4; ++r)
    tile[ty * 4 + r][tx] = mp[(size_t)(k0 + ty * 4 + r) * DD + e0 + tx];
  __syncthreads();
#pragma unroll
  for (int r = 0; r < 4; ++r)
    mht[(size_t)(e0 + ty * 4 + r) * (NK * DD) + k0 + tx] = (f16)tile[tx][ty * 4 + r];
}

// ---------------- phase A: causal Toeplitz conv -> xt[b][t][iL*512+d] (fp16)
// grid: x = 32 (tb 16 x dhalf 2), y = KI, z = b ; 256 threads (4 waves), wave 128t x 64d
// A-frags from global table (coalesced dwordx4); bt dbuf 32KB, g(row)=(row>>1)&3 swizzle (2-way-free)
__global__ __launch_bounds__(256, 2) void k_conv(
    const f16* __restrict__ ut, const f16* __restrict__ afrag,
    f16* __restrict__ xt, int KI, int ibase) {
  __shared__ f16 bt[2][256 * 32];    // 32 KB total
  const int tid = threadIdx.x;
  const int tb = 15 - (blockIdx.x >> 1);   // reversed: big K-loops first
  const int dh = blockIdx.x & 1;
  const int iL = blockIdx.y;
  const int i  = ibase + iL;
  const int b  = blockIdx.z;
  const int t0 = tb * 128;

  const int w = tid >> 6, l = tid & 63;
  const int l15 = l & 15, lq = l >> 4;
  // write-side of involution: logical col = physcol ^ g(row), g(row)=(row>>1)&3, row=l>>2
  const int stage_col = ((l & 3) ^ ((l >> 3) & 3)) * 8;
  const int stage_row = l >> 2;
  const int rd_x = (lq ^ ((l15 >> 1) & 3)) * 16;   // read-side phys col bytes

  const f16* utb = ut + (size_t)b * DD * SL;
  const f16* afi = afrag + ((size_t)i * NPP * 64 + l) * 8;

  auto stage = [&](int buf, int s0) {
#pragma unroll
    for (int j = 0; j < 4; ++j) {
      int row = w * 64 + j * 16 + stage_row;
      gload_lds16(utb + (size_t)(dh * 256 + row) * SL + s0 + stage_col,
                  &bt[buf][(w * 64 + j * 16) * 32]);
    }
  };

  f32x4 acc[8][4];
#pragma unroll
  for (int m = 0; m < 8; ++m)
#pragma unroll
    for (int n = 0; n < 4; ++n) acc[m][n] = (f32x4){0.f, 0.f, 0.f, 0.f};

  const int nIter = 4 * (tb + 1);
  stage(0, 0);
  __syncthreads();
  int cur = 0;

  for (int it = 0; it < nIter; ++it) {
    // A-frags for this iter: p' = 2n + m + 6, n = 4*tb - it  (coalesced global, L1/L2-hot)
    const int pp0 = 2 * (4 * tb - it) + 6;
    const f16* fb = afi + (size_t)pp0 * 512;
    f16x8 A[8];
#pragma unroll
    for (int m = 0; m < 8; ++m) A[m] = *(const f16x8*)(fb + (size_t)m * 512);

    if (it + 1 < nIter) stage(cur ^ 1, (it + 1) * 32);   // prefetch next tile

    f16x8 B[4];
#pragma unroll
    for (int n = 0; n < 4; ++n) {
      int row = w * 64 + n * 16 + l15;
      B[n] = *(const f16x8*)((const char*)&bt[cur][0] + row * 64 + rd_x);
    }

    __builtin_amdgcn_s_setprio(1);
#pragma unroll
    for (int m = 0; m < 8; ++m)
#pragma unroll
      for (int n = 0; n < 4; ++n)
        acc[m][n] = __builtin_amdgcn_mfma_f32_16x16x32_f16(A[m], B[n], acc[m][n], 0, 0, 0);
    __builtin_amdgcn_s_setprio(0);

    __syncthreads();
    cur ^= 1;
  }

  // store xt fp16: D frag: col=lane&15 (d), row=(lane>>4)*4+r (t)
  const size_t rowlen = (size_t)KI * DD;
  const int dbase = dh * 256 + w * 64;
#pragma unroll
  for (int m = 0; m < 8; ++m) {
    int t = t0 + m * 16 + lq * 4;
#pragma unroll
    for (int n = 0; n < 4; ++n) {
      int d = dbase + n * 16 + l15;
      f16* dst = xt + ((size_t)(b * SL + t) * KI + iL) * DD + d;
#pragma unroll
      for (int r = 0; r < 4; ++r)
        dst[(size_t)r * rowlen] = (f16)acc[m][n][r];
    }
  }
}

// ---------------- phase B: out[8192][512] (+)= xt[8192][KI*512] @ mht^T
// BM=128, BN=128, BK=32; grid (4, 64); 256 thr, 4 waves (2x2), wave 64x64 (4x4 frags)
__global__ __launch_bounds__(256, 3) void k_gemm(
    const f16* __restrict__ xt, const f16* __restrict__ mht,
    float* __restrict__ out, int KI, int kc0, int beta) {
  __shared__ f16 at[2][128 * 32];     // 16 KB
  __shared__ f16 btl[2][128 * 32];    // 16 KB
  const int tid = threadIdx.x;
  const int n0 = blockIdx.x * 128;
  const int m0 = blockIdx.y * 128;
  const int w = tid >> 6, l = tid & 63;
  const int l15 = l & 15, lq = l >> 4;
  const int wr = w >> 1, wc = w & 1;
  const int KLEN = KI * DD;
  const int stage_col = ((l & 3) ^ ((l >> 3) & 3)) * 8;
  const int rd_x = (lq ^ ((l15 >> 1) & 3)) * 16;

  auto stage = [&](int buf, int k0) {
#pragma unroll
    for (int j = 0; j < 2; ++j) {
      int row = j * 64 + w * 16 + (l >> 2);
      gload_lds16(xt + (size_t)(m0 + row) * KLEN + k0 + stage_col,
                  &at[buf][j * 2048 + w * 512]);
      gload_lds16(mht + (size_t)(n0 + row) * (NK * DD) + kc0 + k0 + stage_col,
                  &btl[buf][j * 2048 + w * 512]);
    }
  };

  f32x4 acc[4][4];
#pragma unroll
  for (int m = 0; m < 4; ++m)
#pragma unroll
    for (int n = 0; n < 4; ++n) acc[m][n] = (f32x4){0.f, 0.f, 0.f, 0.f};

  const int nIter = KLEN / 32;
  stage(0, 0);
  __syncthreads();
  int cur = 0;

  for (int it = 0; it < nIter; ++it) {
    if (it + 1 < nIter) stage(cur ^ 1, (it + 1) * 32);

    f16x8 Af[4], Bf[4];
#pragma unroll
    for (int m = 0; m < 4; ++m) {
      int row = wr * 64 + m * 16 + l15;
      Af[m] = *(const f16x8*)((const char*)&at[cur][0] + row * 64 + rd_x);
    }
#pragma unroll
    for (int n = 0; n < 4; ++n) {
      int row = wc * 64 + n * 16 + l15;
      Bf[n] = *(const f16x8*)((const char*)&btl[cur][0] + row * 64 + rd_x);
    }

    __builtin_amdgcn_s_setprio(1);
#pragma unroll
    for (int m = 0; m < 4; ++m)
#pragma unroll
      for (int n = 0; n < 4; ++n)
        acc[m][n] = __builtin_amdgcn_mfma_f32_16x16x32_f16(Af[m], Bf[n], acc[m][n], 0, 0, 0);
    __builtin_amdgcn_s_setprio(0);

    __syncthreads();
    cur ^= 1;
  }

#pragma unroll
  for (int m = 0; m < 4; ++m) {
    int row = m0 + wr * 64 + m * 16 + lq * 4;
#pragma unroll
    for (int n = 0; n < 4; ++n) {
      int e = n0 + wc * 64 + n * 16 + l15;
      float* dst = out + (size_t)row * DD + e;
#pragma unroll
      for (int r = 0; r < 4; ++r) {
        float v = acc[m][n][r];
        if (beta) v += dst[(size_t)r * DD];
        dst[(size_t)r * DD] = v;
      }
    }
  }
}

extern "C" void kernel_launch(void* const* d_in, const int* in_sizes, int n_in,
                              void* d_out, int out_size, void* d_ws, size_t ws_size,
                              hipStream_t stream) {
  const float* u    = (const float*)d_in[0];  // [4,2048,512]
  const float* ev   = (const float*)d_in[1];  // [24]
  const float* evec = (const float*)d_in[2];  // [2048,24]
  const float* mp   = (const float*)d_in[3];  // [12288,512]
  float* out = (float*)d_out;
  char* ws = (char*)d_ws;

  const size_t UT_OFF  = 0;                        // 8,388,608 B
  const size_t MHT_OFF = 8388608;                  // 12,582,912 B
  const size_t AF_OFF  = 20971520;                 // 24*134*64*8*2 = 3,293,184 B
  const size_t XT_OFF  = 24264704;

  f16* ut    = (f16*)(ws + UT_OFF);
  f16* mht   = (f16*)(ws + MHT_OFF);
  f16* afrag = (f16*)(ws + AF_OFF);
  f16* xt    = (f16*)(ws + XT_OFF);

  // pick largest i-chunk that fits the workspace
  int KI = 1;
  const int cands[8] = {24, 12, 8, 6, 4, 3, 2, 1};
  for (int ci = 0; ci < 8; ++ci) {
    size_t need = XT_OFF + (size_t)cands[ci] * 8388608ull;
    if (need <= ws_size) { KI = cands[ci]; break; }
  }
  const int NC = NK / KI;

  k_afrag<<<dim3(24, NPP), 64, 0, stream>>>(ev, evec, afrag);
  k_tu<<<dim3(SL / 32, DD / 32, BSZ), dim3(32, 8), 0, stream>>>(u, ut);
  k_tm<<<dim3((NK * DD) / 32, DD / 32), dim3(32, 8), 0, stream>>>(mp, mht);

  for (int c = 0; c < NC; ++c) {
    k_conv<<<dim3(32, KI, BSZ), 256, 0, stream>>>(ut, afrag, xt, KI, c * KI);
    k_gemm<<<dim3(DD / 128, (BSZ * SL) / 128), 256, 0, stream>>>(
        xt, mht, out, KI, c * KI * DD, c > 0);
  }
}